// Round 4
// baseline (325.320 us; speedup 1.0000x reference)
//
#include <hip/hip_runtime.h>

#define N 8192
#define M 8192
#define D 256

typedef unsigned short ushort_t;
typedef __attribute__((ext_vector_type(8))) short short8;
typedef __attribute__((ext_vector_type(4))) float floatx4;

__device__ __forceinline__ unsigned short f2bf(float f) {
  unsigned int u = __float_as_uint(f);
  u += 0x7fffu + ((u >> 16) & 1u);   // round-to-nearest-even
  return (unsigned short)(u >> 16);
}

// prep writes xb/sb in MFMA-FRAGMENT-LANE order so the gemm can load fragments
// straight from global to VGPRs with single coalesced dwordx4 per fragment
// (no LDS staging at all -- inputs are 8 MB, L2/L3-resident; Common-mistake #7).
//
// Layout: row r, element k  ->  byte
//   g = r>>6 (64-row group), sub = (r>>4)&3 (16-row panel), m = r&15
//   c = k>>5 (32-k chunk),   q = (k>>3)&3,                  b = k&7
//   byte = g*32768 + (c*4 + sub)*1024 + q*256 + m*16 + b*2
// Within each 1KB tile (g, c, sub): lane l = q*16 + m reads bytes l*16..+16,
// which is exactly the 16x16x32 bf16 A/B fragment mapping (row = lane&15,
// k-offset = (lane>>4)*8). One global_load_dwordx4 at base + lane*16 = one
// fragment, perfectly coalesced (dense 1KB).
__global__ __launch_bounds__(256) void prep_kernel(const float* __restrict__ x,
                                                   const float* __restrict__ s,
                                                   ushort_t* __restrict__ xb,
                                                   ushort_t* __restrict__ sb,
                                                   float* __restrict__ xn,
                                                   float* __restrict__ sn) {
  int gw = blockIdx.x * 4 + (threadIdx.x >> 6);
  int lane = threadIdx.x & 63;
  const float* src;
  ushort_t* dst;
  float* nrm;
  int row;
  if (gw < N) { src = x; dst = xb; nrm = xn; row = gw; }
  else        { src = s; dst = sb; nrm = sn; row = gw - N; }
  float4 v = ((const float4*)(src + (size_t)row * D))[lane];  // k = 4*lane..+3
  float ss = v.x * v.x + v.y * v.y + v.z * v.z + v.w * v.w;
  ushort4 o;
  o.x = f2bf(v.x); o.y = f2bf(v.y); o.z = f2bf(v.z); o.w = f2bf(v.w);
  const int g = row >> 6;
  const int sub = (row >> 4) & 3;
  const int m = row & 15;
  const int c = lane >> 3;        // k-chunk of this lane's 4 elems
  const int q = (lane >> 1) & 3;  // k-quarter within chunk
  size_t off = (size_t)g * 32768 +
               (size_t)((c * 4 + sub) * 1024 + q * 256 + m * 16 + (lane & 1) * 8);
  *(ushort4*)((char*)dst + off) = o;
#pragma unroll
  for (int offs = 32; offs > 0; offs >>= 1) ss += __shfl_down(ss, offs);
  if (lane == 0) nrm[row] = ss;
}

// 128x128 C-tile, 4 waves (2x2), each wave computes a 64x64 sub-tile reading
// its A/B fragments DIRECTLY from global (L2-hot, fragment-ordered). No K-loop
// barriers, no global_load_lds, no vmcnt(0) drains: register-destined loads
// get per-use counted s_waitcnt from the compiler (G7), giving the AITER-style
// load<->MFMA interleave that rounds 1-3 could not impose on the LDS path.
// Only LDS use: 1 KB of row/col norms, one barrier AFTER the K-loop.
__global__ __launch_bounds__(256, 3) void rbf_gemm(const ushort_t* __restrict__ X,
                                                   const ushort_t* __restrict__ S,
                                                   const float* __restrict__ xn,
                                                   const float* __restrict__ sn,
                                                   float* __restrict__ out) {
  __shared__ float nS[256];  // [0:128) row norms, [128:256) col norms

  const int tid = threadIdx.x;
  const int lane = tid & 63;
  const int wave = tid >> 6;

  // XCD-chunked bijective swizzle (T1): 4096 wgs % 8 == 0, 512 contiguous/XCD
  // -> each XCD's hot B slice (~4 MB) stays in its own L2.
  const int wg = blockIdx.y * 64 + blockIdx.x;
  const int swz = (wg & 7) * 512 + (wg >> 3);
  const int by = swz >> 6;
  const int bx = swz & 63;

  if (tid < 128) nS[tid] = xn[by * 128 + tid];
  else           nS[tid - 128 + 128] = sn[bx * 128 + (tid - 128)];

  // Wave's 64-row groups in the fragment-ordered images.
  const char* aw = (const char*)X + (size_t)(by * 2 + (wave >> 1)) * 32768 + lane * 16;
  const char* bw = (const char*)S + (size_t)(bx * 2 + (wave & 1)) * 32768 + lane * 16;

  floatx4 acc[4][4];
#pragma unroll
  for (int i = 0; i < 4; ++i)
#pragma unroll
    for (int j = 0; j < 4; ++j) acc[i][j] = (floatx4){0.f, 0.f, 0.f, 0.f};

  // K-loop: 8 chunks of 32; per chunk 8 coalesced 1KB fragment loads + 16 MFMA.
  // Fully unrolled, all-static indexing (rule #20); compiler software-pipelines
  // chunk c+1 loads under chunk c MFMAs with counted vmcnt.
#pragma unroll
  for (int c = 0; c < 8; ++c) {
    short8 af[4], bf[4];
#pragma unroll
    for (int i = 0; i < 4; ++i)
      af[i] = *(const short8*)(aw + (c * 4 + i) * 1024);
#pragma unroll
    for (int j = 0; j < 4; ++j)
      bf[j] = *(const short8*)(bw + (c * 4 + j) * 1024);
#pragma unroll
    for (int i = 0; i < 4; ++i)
#pragma unroll
      for (int j = 0; j < 4; ++j)
        acc[i][j] = __builtin_amdgcn_mfma_f32_16x16x32_bf16(af[i], bf[j],
                                                            acc[i][j], 0, 0, 0);
  }

  __syncthreads();  // nS ds_writes visible; K-loop loads already consumed

  // Epilogue: sq = ||x||^2 + ||s||^2 - 2*cross, clamped; out = exp(-sq/D).
  // C/D layout (m89/m91-verified): col = lane&15, row = (lane>>4)*4 + reg.
  // Nontemporal: 256 MB streamed once, never re-read -> keep inputs in L2.
  const int wr = (wave >> 1) * 64;
  const int wc = (wave & 1) * 64;
  const int q4 = lane >> 4;
  const int m16 = lane & 15;
  const float cexp = -1.0f / (float)D;
#pragma unroll
  for (int i = 0; i < 4; ++i) {
#pragma unroll
    for (int j = 0; j < 4; ++j) {
#pragma unroll
      for (int r = 0; r < 4; ++r) {
        const int rl = wr + i * 16 + q4 * 4 + r;
        const int cl = wc + j * 16 + m16;
        float sq = nS[rl] + nS[128 + cl] - 2.0f * acc[i][j][r];
        sq = fmaxf(sq, 0.0f);
        __builtin_nontemporal_store(
            __expf(cexp * sq),
            out + (size_t)(by * 128 + rl) * M + (bx * 128 + cl));
      }
    }
  }
}

extern "C" void kernel_launch(void* const* d_in, const int* in_sizes, int n_in,
                              void* d_out, int out_size, void* d_ws, size_t ws_size,
                              hipStream_t stream) {
  const float* x = (const float*)d_in[0];
  const float* s = (const float*)d_in[1];
  float* out = (float*)d_out;
  char* ws = (char*)d_ws;
  ushort_t* xb = (ushort_t*)ws;                           // 4 MB bf16 X (frag-tiled)
  ushort_t* sb = (ushort_t*)(ws + (size_t)N * D * 2);     // 4 MB bf16 S (frag-tiled)
  float* xn = (float*)(ws + (size_t)(N + M) * D * 2);     // 32 KB
  float* sn = xn + N;                                     // 32 KB

  prep_kernel<<<(N + M) / 4, 256, 0, stream>>>(x, s, xb, sb, xn, sn);
  dim3 grid(M / 128, N / 128);
  rbf_gemm<<<grid, 256, 0, stream>>>(xb, sb, xn, sn, out);
}

// Round 5
// 313.641 us; speedup vs baseline: 1.0372x; 1.0372x over previous
//
#include <hip/hip_runtime.h>

#define N 8192
#define M 8192
#define D 256

typedef unsigned short ushort_t;
typedef __attribute__((ext_vector_type(8))) short short8;
typedef __attribute__((ext_vector_type(4))) float floatx4;

__device__ __forceinline__ unsigned short f2bf(float f) {
  unsigned int u = __float_as_uint(f);
  u += 0x7fffu + ((u >> 16) & 1u);   // round-to-nearest-even
  return (unsigned short)(u >> 16);
}

// One wave per row: fp32 norm (full precision) + bf16 cast of the row.
// (EXACT round-0 prep: plain row-major bf16 image.)
__global__ __launch_bounds__(256) void prep_kernel(const float* __restrict__ x,
                                                   const float* __restrict__ s,
                                                   ushort_t* __restrict__ xb,
                                                   ushort_t* __restrict__ sb,
                                                   float* __restrict__ xn,
                                                   float* __restrict__ sn) {
  int gw = blockIdx.x * 4 + (threadIdx.x >> 6);
  int lane = threadIdx.x & 63;
  const float* src;
  ushort_t* dst;
  float* nrm;
  int row;
  if (gw < N) { src = x; dst = xb; nrm = xn; row = gw; }
  else        { src = s; dst = sb; nrm = sn; row = gw - N; }
  float4 v = ((const float4*)(src + (size_t)row * D))[lane];  // 64 lanes x 4 = 256
  float ss = v.x * v.x + v.y * v.y + v.z * v.z + v.w * v.w;
  ushort4 o;
  o.x = f2bf(v.x); o.y = f2bf(v.y); o.z = f2bf(v.z); o.w = f2bf(v.w);
  *(ushort4*)(dst + (size_t)row * D + lane * 4) = o;
#pragma unroll
  for (int off = 32; off > 0; off >>= 1) ss += __shfl_down(ss, off);
  if (lane == 0) nrm[row] = ss;
}

// 128x128 C-tile, 4 waves (2x2), each wave 4x4 of 16x16x32 bf16 MFMA.
// Staging/K-loop structure is BYTE-IDENTICAL to the best-known (round-0)
// kernel: global_load_lds both operands, BK=128, 2 rounds, plain barriers,
// 2 blocks/CU (every pipeline variant tried in rounds 1-4 was worse).
// ONLY change: MFMA operands are SWAPPED -- mfma(b_frag, a_frag) computes the
// transposed fragment, so C/D mapping (col=lane&15 -> B-op rows = X rows;
// row=(lane>>4)*4+reg -> A-op rows = S cols) gives each lane 4 CONSECUTIVE
// output columns per fragment => one float4 nontemporal store per fragment:
// 16 dwordx4 stores/thread instead of 64 scalar dword stores (1/4 the store
// issue + address VALU), same 64B coalescing segments.
__global__ __launch_bounds__(256, 2) void rbf_gemm(const ushort_t* __restrict__ X,
                                                   const ushort_t* __restrict__ S,
                                                   const float* __restrict__ xn,
                                                   const float* __restrict__ sn,
                                                   float* __restrict__ out) {
  // chunked layout: [chunk 0..3][row 0..127][k 0..31], lane-linear per
  // global_load_lds (wave-uniform base + lane*16B), no padding.
  __shared__ __attribute__((aligned(16))) ushort_t As[4 * 128 * 32];
  __shared__ __attribute__((aligned(16))) ushort_t Bs[4 * 128 * 32];
  __shared__ __attribute__((aligned(16))) float xnS[128];
  __shared__ __attribute__((aligned(16))) float snS[128];

  const int tid = threadIdx.x;
  const int lane = tid & 63;
  const int wave = tid >> 6;
  const int bx = blockIdx.x;  // col block (support)
  const int by = blockIdx.y;  // row block (x)

  if (tid < 128) xnS[tid] = xn[by * 128 + tid];
  else           snS[tid - 128] = sn[bx * 128 + (tid - 128)];

  const int wr = (wave >> 1) * 64;  // wave row offset in tile
  const int wc = (wave & 1) * 64;   // wave col offset in tile

  // Staging: wave covers tile rows [wave*32, wave*32+32). Inst q in {0,1}:
  // lane l -> row wave*32 + q*16 + l/4, cols (l&3)*8 .. +8 (16 B).
  const int srow = wave * 32 + (lane >> 2);
  const int scol = (lane & 3) * 8;
  const ushort_t* gA = X + (size_t)(by * 128 + srow) * D + scol;
  const ushort_t* gB = S + (size_t)(bx * 128 + srow) * D + scol;

  const int q4 = lane >> 4;   // 0..3
  const int m16 = lane & 15;  // 0..15

  floatx4 acc[4][4];
#pragma unroll
  for (int i = 0; i < 4; ++i)
#pragma unroll
    for (int j = 0; j < 4; ++j) acc[i][j] = (floatx4){0.f, 0.f, 0.f, 0.f};

#pragma unroll
  for (int r = 0; r < 2; ++r) {
    const int kb = r * 128;
    __syncthreads();  // previous round's readers done before overwrite
#pragma unroll
    for (int c = 0; c < 4; ++c) {
      const int k0 = kb + c * 32;
      ushort_t* lA = As + c * 4096 + wave * 1024;
      ushort_t* lB = Bs + c * 4096 + wave * 1024;
      __builtin_amdgcn_global_load_lds(
          (const __attribute__((address_space(1))) void*)(gA + k0),
          (__attribute__((address_space(3))) void*)(lA), 16, 0, 0);
      __builtin_amdgcn_global_load_lds(
          (const __attribute__((address_space(1))) void*)(gA + (size_t)16 * D + k0),
          (__attribute__((address_space(3))) void*)(lA + 512), 16, 0, 0);
      __builtin_amdgcn_global_load_lds(
          (const __attribute__((address_space(1))) void*)(gB + k0),
          (__attribute__((address_space(3))) void*)(lB), 16, 0, 0);
      __builtin_amdgcn_global_load_lds(
          (const __attribute__((address_space(1))) void*)(gB + (size_t)16 * D + k0),
          (__attribute__((address_space(3))) void*)(lB + 512), 16, 0, 0);
    }
    __syncthreads();  // compiler emits s_waitcnt vmcnt(0) before s_barrier

#pragma unroll
    for (int c = 0; c < 4; ++c) {
      const ushort_t* cA = As + c * 4096;
      const ushort_t* cB = Bs + c * 4096;
      short8 a_frag[4], b_frag[4];
#pragma unroll
      for (int i = 0; i < 4; ++i)
        a_frag[i] = *(const short8*)(cA + (wr + i * 16 + m16) * 32 + q4 * 8);
#pragma unroll
      for (int j = 0; j < 4; ++j)
        b_frag[j] = *(const short8*)(cB + (wc + j * 16 + m16) * 32 + q4 * 8);
#pragma unroll
      for (int i = 0; i < 4; ++i)
#pragma unroll
        for (int j = 0; j < 4; ++j)
          acc[i][j] = __builtin_amdgcn_mfma_f32_16x16x32_bf16(b_frag[j], a_frag[i],
                                                              acc[i][j], 0, 0, 0);
    }
  }

  // Epilogue (swapped-operand layout): for fragment (i,j), lane holds
  //   X row   rl = wr + i*16 + m16            (fixed per lane)
  //   S cols  wc + j*16 + q4*4 + r, r=0..3    (4 consecutive -> float4 store)
  // Hoist norms to registers first (one-time LDS reads; colN as aligned b128).
  float rowN[4];
  floatx4 colN[4];
#pragma unroll
  for (int i = 0; i < 4; ++i) rowN[i] = xnS[wr + i * 16 + m16];
#pragma unroll
  for (int j = 0; j < 4; ++j)
    colN[j] = *(const floatx4*)&snS[wc + j * 16 + q4 * 4];

  const float cexp = -1.0f / (float)D;
#pragma unroll
  for (int i = 0; i < 4; ++i) {
    const int rl = wr + i * 16 + m16;
    float* orow = out + (size_t)(by * 128 + rl) * M + bx * 128;
#pragma unroll
    for (int j = 0; j < 4; ++j) {
      floatx4 v;
#pragma unroll
      for (int r = 0; r < 4; ++r) {
        float sq = rowN[i] + colN[j][r] - 2.0f * acc[i][j][r];
        sq = fmaxf(sq, 0.0f);
        v[r] = __expf(cexp * sq);
      }
      // 256 MB streamed once, never re-read: nontemporal keeps the 8 MB
      // input image resident in L2 for the staging reads.
      __builtin_nontemporal_store(v, (floatx4*)(orow + wc + j * 16 + q4 * 4));
    }
  }
}

extern "C" void kernel_launch(void* const* d_in, const int* in_sizes, int n_in,
                              void* d_out, int out_size, void* d_ws, size_t ws_size,
                              hipStream_t stream) {
  const float* x = (const float*)d_in[0];
  const float* s = (const float*)d_in[1];
  float* out = (float*)d_out;
  char* ws = (char*)d_ws;
  ushort_t* xb = (ushort_t*)ws;                           // 4 MB bf16 X
  ushort_t* sb = (ushort_t*)(ws + (size_t)N * D * 2);     // 4 MB bf16 S
  float* xn = (float*)(ws + (size_t)(N + M) * D * 2);     // 32 KB
  float* sn = xn + N;                                     // 32 KB

  prep_kernel<<<(N + M) / 4, 256, 0, stream>>>(x, s, xb, sb, xn, sn);
  dim3 grid(M / 128, N / 128);
  rbf_gemm<<<grid, 256, 0, stream>>>(xb, sb, xn, sn, out);
}

// Round 6
// 295.196 us; speedup vs baseline: 1.1020x; 1.0625x over previous
//
#include <hip/hip_runtime.h>

#define N 8192
#define M 8192
#define D 256

typedef unsigned short ushort_t;
typedef __attribute__((ext_vector_type(8))) short short8;
typedef __attribute__((ext_vector_type(4))) float floatx4;

__device__ __forceinline__ unsigned short f2bf(float f) {
  unsigned int u = __float_as_uint(f);
  u += 0x7fffu + ((u >> 16) & 1u);   // round-to-nearest-even
  return (unsigned short)(u >> 16);
}

// prep writes xb/sb as 1KB MFMA-FRAGMENT TILES (layout HW-verified in round 4):
//   row r, elem k -> byte  g*32768 + (c*4 + sub)*1024 + q*256 + m*16 + b*2
//   g = r>>6, sub = (r>>4)&3, m = r&15, c = k>>5, q = (k>>3)&3, b = k&7
// Within each 1KB tile, byte l*16 holds exactly lane l's 16x16x32 bf16
// fragment slice (row = l&15, k-half = l>>4). So the gemm stages contiguous
// 1KB tiles (global_load_lds, linear dest per m104) and fragment ds_reads are
// wave-uniform base + lane*16: lane-linear => ZERO bank conflicts (the R0
// [row][32] layout was an 8-way conflict: 64B row stride puts 16 lanes on 2
// banks, ~2.9x per m136 -- the modeled dominant cost of the R0 gemm).
__global__ __launch_bounds__(256) void prep_kernel(const float* __restrict__ x,
                                                   const float* __restrict__ s,
                                                   ushort_t* __restrict__ xb,
                                                   ushort_t* __restrict__ sb,
                                                   float* __restrict__ xn,
                                                   float* __restrict__ sn) {
  int gw = blockIdx.x * 4 + (threadIdx.x >> 6);
  int lane = threadIdx.x & 63;
  const float* src;
  ushort_t* dst;
  float* nrm;
  int row;
  if (gw < N) { src = x; dst = xb; nrm = xn; row = gw; }
  else        { src = s; dst = sb; nrm = sn; row = gw - N; }
  float4 v = ((const float4*)(src + (size_t)row * D))[lane];  // k = 4*lane..+3
  float ss = v.x * v.x + v.y * v.y + v.z * v.z + v.w * v.w;
  ushort4 o;
  o.x = f2bf(v.x); o.y = f2bf(v.y); o.z = f2bf(v.z); o.w = f2bf(v.w);
  const int g = row >> 6;
  const int sub = (row >> 4) & 3;
  const int m = row & 15;
  const int c = lane >> 3;        // k-chunk of this lane's 4 elems
  const int q = (lane >> 1) & 3;  // k-quarter within chunk
  size_t off = (size_t)g * 32768 +
               (size_t)((c * 4 + sub) * 1024 + q * 256 + m * 16 + (lane & 1) * 8);
  *(ushort4*)((char*)dst + off) = o;
#pragma unroll
  for (int offs = 32; offs > 0; offs >>= 1) ss += __shfl_down(ss, offs);
  if (lane == 0) nrm[row] = ss;
}

// EXACT round-0 structure: 128x128 C-tile, 4 waves (2x2), BK=128, 2 rounds,
// plain __syncthreads, global_load_lds both operands, 64KB LDS -> 2 blocks/CU,
// plain mfma(a,b) order, scalar-store epilogue (no nontemporal), no grid
// swizzle. ONLY change vs round 0: the LDS image is fragment-tiled (see prep)
// so staging loads are contiguous 1KB and fragment ds_read_b128s are
// lane-linear (conflict-free) with immediate-offset addressing.
__global__ __launch_bounds__(256, 2) void rbf_gemm(const ushort_t* __restrict__ X,
                                                   const ushort_t* __restrict__ S,
                                                   const float* __restrict__ xn,
                                                   const float* __restrict__ sn,
                                                   float* __restrict__ out) {
  // tile t = c*8 + sub (1 KB each): c = k-chunk 0..3 of this round,
  // sub = 16-row panel 0..7. 32 KB per operand.
  __shared__ __attribute__((aligned(16))) ushort_t As[4 * 128 * 32];
  __shared__ __attribute__((aligned(16))) ushort_t Bs[4 * 128 * 32];
  __shared__ float xnS[128];
  __shared__ float snS[128];

  const int tid = threadIdx.x;
  const int lane = tid & 63;
  const int wave = tid >> 6;
  const int bx = blockIdx.x;  // col block (support)
  const int by = blockIdx.y;  // row block (x)

  if (tid < 128) xnS[tid] = xn[by * 128 + tid];
  else           snS[tid - 128] = sn[bx * 128 + (tid - 128)];

  const int wr = (wave >> 1) * 64;  // wave row offset in tile
  const int wc = (wave & 1) * 64;   // wave col offset in tile
  const int q4 = lane >> 4;   // 0..3
  const int m16 = lane & 15;  // 0..15

  // Staging: wave w covers global k-chunk (r*4 + w) -> LDS chunk w.
  // 8 A-tiles + 8 B-tiles per wave per round, each a contiguous 1KB.
  const char* gAb = (const char*)X + (size_t)by * 65536 + lane * 16;
  const char* gBb = (const char*)S + (size_t)bx * 65536 + lane * 16;
  char* lAb = (char*)As + wave * 8192;
  char* lBb = (char*)Bs + wave * 8192;

  floatx4 acc[4][4];
#pragma unroll
  for (int i = 0; i < 4; ++i)
#pragma unroll
    for (int j = 0; j < 4; ++j) acc[i][j] = (floatx4){0.f, 0.f, 0.f, 0.f};

#pragma unroll
  for (int r = 0; r < 2; ++r) {
    const int kc4 = (r * 4 + wave) * 4;  // global tile index base of this chunk
    __syncthreads();  // previous round's readers done before overwrite
#pragma unroll
    for (int sub = 0; sub < 8; ++sub) {
      const size_t gsel = (size_t)(sub >> 2) * 32768;  // 64-row group
      const int s4 = sub & 3;
      __builtin_amdgcn_global_load_lds(
          (const __attribute__((address_space(1))) void*)(gAb + gsel + ((kc4 + s4) << 10)),
          (__attribute__((address_space(3))) void*)(lAb + (sub << 10)), 16, 0, 0);
      __builtin_amdgcn_global_load_lds(
          (const __attribute__((address_space(1))) void*)(gBb + gsel + ((kc4 + s4) << 10)),
          (__attribute__((address_space(3))) void*)(lBb + (sub << 10)), 16, 0, 0);
    }
    __syncthreads();  // compiler emits s_waitcnt vmcnt(0) before s_barrier

#pragma unroll
    for (int c = 0; c < 4; ++c) {
      const char* cA = (const char*)As + c * 8192 + lane * 16;
      const char* cB = (const char*)Bs + c * 8192 + lane * 16;
      short8 a_frag[4], b_frag[4];
#pragma unroll
      for (int i = 0; i < 4; ++i)
        a_frag[i] = *(const short8*)(cA + ((wave >> 1) * 4 + i) * 1024);
#pragma unroll
      for (int j = 0; j < 4; ++j)
        b_frag[j] = *(const short8*)(cB + ((wave & 1) * 4 + j) * 1024);
#pragma unroll
      for (int i = 0; i < 4; ++i)
#pragma unroll
        for (int j = 0; j < 4; ++j)
          acc[i][j] = __builtin_amdgcn_mfma_f32_16x16x32_bf16(a_frag[i], b_frag[j],
                                                              acc[i][j], 0, 0, 0);
    }
  }

  // Epilogue: EXACT round-0. sq = ||x||^2 + ||s||^2 - 2*cross, clamped;
  // out = exp(-sq/D). C/D layout (m89/m91): col = lane&15, row = (lane>>4)*4+reg.
  const float cexp = -1.0f / (float)D;
#pragma unroll
  for (int i = 0; i < 4; ++i) {
#pragma unroll
    for (int j = 0; j < 4; ++j) {
#pragma unroll
      for (int r = 0; r < 4; ++r) {
        const int rl = wr + i * 16 + q4 * 4 + r;
        const int cl = wc + j * 16 + m16;
        float sq = xnS[rl] + snS[cl] - 2.0f * acc[i][j][r];
        sq = fmaxf(sq, 0.0f);
        out[(size_t)(by * 128 + rl) * M + (bx * 128 + cl)] = __expf(cexp * sq);
      }
    }
  }
}

extern "C" void kernel_launch(void* const* d_in, const int* in_sizes, int n_in,
                              void* d_out, int out_size, void* d_ws, size_t ws_size,
                              hipStream_t stream) {
  const float* x = (const float*)d_in[0];
  const float* s = (const float*)d_in[1];
  float* out = (float*)d_out;
  char* ws = (char*)d_ws;
  ushort_t* xb = (ushort_t*)ws;                           // 4 MB bf16 X (frag-tiled)
  ushort_t* sb = (ushort_t*)(ws + (size_t)N * D * 2);     // 4 MB bf16 S (frag-tiled)
  float* xn = (float*)(ws + (size_t)(N + M) * D * 2);     // 32 KB
  float* sn = xn + N;                                     // 32 KB

  prep_kernel<<<(N + M) / 4, 256, 0, stream>>>(x, s, xb, sb, xn, sn);
  dim3 grid(M / 128, N / 128);
  rbf_gemm<<<grid, 256, 0, stream>>>(xb, sb, xn, sn, out);
}